// Round 17
// baseline (2190.422 us; speedup 1.0000x reference)
//
#include <hip/hip_runtime.h>
#include <cstddef>

#define HD 512
#define FF 2048
#define VOUT 1024
#define KJOINT 2048

typedef short bf16x8 __attribute__((ext_vector_type(8)));
typedef float f32x4 __attribute__((ext_vector_type(4)));

__device__ inline unsigned short f2bf(float f) {
  union { float f; unsigned u; } c{f};
  unsigned r = c.u + 0x7FFFu + ((c.u >> 16) & 1u);
  return (unsigned short)(r >> 16);
}
__device__ inline float bf2f(unsigned short h) {
  union { unsigned u; float f; } c{(unsigned)h << 16};
  return c.f;
}
__device__ inline float fast_tanh(float x) {
  float e = __expf(2.f * x);
  return 1.f - 2.f / (e + 1.f);
}

// ---------------------------------------------------------------------------
// Merged embeddings: blocks 0..1023 audio (b,t), 1024..1279 label (b,u).
// ---------------------------------------------------------------------------
__global__ __launch_bounds__(256) void embed_all_kernel(
    const float* __restrict__ inp, const float* __restrict__ w,
    const float* __restrict__ bias, const float* __restrict__ pos,
    const int* __restrict__ labels, const float* __restrict__ word,
    const float* __restrict__ lpos,
    float* __restrict__ x, unsigned short* __restrict__ xbf) {
  int blk = blockIdx.x;
  int tid = threadIdx.x;
  if (blk < 1024) {
    int b = blk >> 8, t = blk & 255;
    __shared__ __align__(16) float col[80];
    if (tid < 80) col[tid] = inp[((size_t)b * 80 + tid) * 256 + t];
    __syncthreads();
    for (int h = tid; h < HD; h += 256) {
      const float* wr = w + (size_t)h * 80;
      float acc = 0.f;
#pragma unroll
      for (int c = 0; c < 80; c++) acc += col[c] * wr[c];
      float v = acc + bias[h] + pos[(size_t)t * HD + h];
      x[(size_t)blk * HD + h] = v;
      if (xbf) xbf[(size_t)blk * HD + h] = f2bf(v);
    }
  } else {
    int bu = blk - 1024;
    int u = bu & 63;
    int id = labels[bu];
    for (int h = tid; h < HD; h += 256) {
      float v = word[(size_t)id * HD + h] + lpos[(size_t)u * HD + h];
      x[(size_t)blk * HD + h] = v;
      if (xbf) xbf[(size_t)blk * HD + h] = f2bf(v);
    }
  }
}

// ---------------------------------------------------------------------------
// Weight pack: [N rows, K] f32 (stride ld) -> bf16 fragment order
// dst[(colg*(K/64)+kstep)*1024 + chunk*512 + lane*8 + j].
// ---------------------------------------------------------------------------
__device__ __forceinline__ void pack_one(
    const float* __restrict__ in, int ld, int K,
    unsigned short* __restrict__ out, int g) {
  int kb = K >> 3;
  int col = g / kb;
  int k8 = g - col * kb;
  const float* src = in + (size_t)col * ld + k8 * 8;
  float4 v0 = *(const float4*)(src);
  float4 v1 = *(const float4*)(src + 4);
  int colg = col >> 4, cl = col & 15;
  int kstep = k8 >> 3;
  int lgrp = (k8 & 7) >> 1;
  int chunk = k8 & 1;
  int lane = lgrp * 16 + cl;
  unsigned short* dst =
      out + ((size_t)(colg * (K >> 6) + kstep)) * 1024 + chunk * 512 + lane * 8;
  *(ushort4*)(dst) = ushort4{f2bf(v0.x), f2bf(v0.y), f2bf(v0.z), f2bf(v0.w)};
  *(ushort4*)(dst + 4) = ushort4{f2bf(v1.x), f2bf(v1.y), f2bf(v1.z), f2bf(v1.w)};
}

__global__ __launch_bounds__(256) void pack_w_kernel(
    const float* __restrict__ in, int ld, int K,
    unsigned short* __restrict__ out) {
  pack_one(in, ld, K, out, blockIdx.x * 256 + threadIdx.x);
}

struct PackSeg {
  const float* src;
  unsigned short* dst;
  int ld;
  int K;
  int nel8;
};
struct PackArgs {
  PackSeg s[11];
};

__global__ __launch_bounds__(256) void pack_all_kernel(PackArgs a) {
  int g = blockIdx.x * 256 + threadIdx.x;
#pragma unroll
  for (int i = 0; i < 11; i++) {
    if (g < a.s[i].nel8) {
      pack_one(a.s[i].src, a.s[i].ld, a.s[i].K, a.s[i].dst, g);
      return;
    }
    g -= a.s[i].nel8;
  }
}

// ---------------------------------------------------------------------------
// Packed-B bf16 GEMM with optional split-K (part = blockIdx.z):
// tile 64 rows x 64 cols, 256 thr = 4 waves, wave = 64x16 cols.
// ---------------------------------------------------------------------------
template <int ACT, int OUT_BF16>
__global__ __launch_bounds__(256) void gemmp_kernel(
    const unsigned short* __restrict__ A, int lda,
    const unsigned short* __restrict__ B0, const unsigned short* __restrict__ B1,
    const float* __restrict__ bias0, const float* __restrict__ bias1,
    void* __restrict__ Cout, int ldc, int K, int Msplit,
    int ksn, size_t partStride) {
  __shared__ char AsB[64 * 128];  // 8 KB
  int tid = threadIdx.x;
  int by = blockIdx.y * 64, bx = blockIdx.x * 64;
  int part = blockIdx.z;
  const unsigned short* Bp = (by < Msplit) ? B0 : B1;
  const float* bias = (by < Msplit) ? bias0 : bias1;
  if (part != 0) bias = nullptr;
  int lane = tid & 63, w = tid >> 6;
  int ksteps = K >> 6;
  int ks0 = part * ksn;
  int ksend = ks0 + ksn;

  int arow = tid >> 2;
  int ak = (tid & 3) * 16;
  const unsigned short* Ap = A + (size_t)(by + arow) * lda + ak;
  int aswz = (arow & 7) << 4;
  char* As_w0 = AsB + arow * 128 + ((ak * 2) ^ aswz);
  char* As_w1 = AsB + arow * 128 + (((ak * 2) + 16) ^ aswz);

  int fswz = ((lane & 7) << 4);
  const char* As_rh0 = AsB + (lane & 15) * 128 + (((lane >> 4) * 32) ^ fswz);
  const char* As_rh1 = AsB + (lane & 15) * 128 + ((((lane >> 4) * 32) + 16) ^ fswz);

  int cg = (bx >> 4) + w;
  const unsigned short* Bl = Bp + ((size_t)cg * ksteps) * 1024 + lane * 8;

  f32x4 acc[4] = {};
  bf16x8 pa0 = *(const bf16x8*)(Ap + ks0 * 64);
  bf16x8 pa1 = *(const bf16x8*)(Ap + ks0 * 64 + 8);
  for (int ks = ks0; ks < ksend; ks++) {
    const unsigned short* bp = Bl + (size_t)ks * 1024;
    bf16x8 b0 = *(const bf16x8*)(bp);
    bf16x8 b1 = *(const bf16x8*)(bp + 512);
    __syncthreads();
    *(bf16x8*)As_w0 = pa0;
    *(bf16x8*)As_w1 = pa1;
    __syncthreads();
    if (ks + 1 < ksend) {
      pa0 = *(const bf16x8*)(Ap + (ks + 1) * 64);
      pa1 = *(const bf16x8*)(Ap + (ks + 1) * 64 + 8);
    }
#pragma unroll
    for (int mi = 0; mi < 4; mi++) {
      bf16x8 af0 = *(const bf16x8*)(As_rh0 + mi * 16 * 128);
      bf16x8 af1 = *(const bf16x8*)(As_rh1 + mi * 16 * 128);
      acc[mi] = __builtin_amdgcn_mfma_f32_16x16x32_bf16(af0, b0, acc[mi], 0, 0, 0);
      acc[mi] = __builtin_amdgcn_mfma_f32_16x16x32_bf16(af1, b1, acc[mi], 0, 0, 0);
    }
  }
  int colo = bx + w * 16 + (lane & 15);
  float bi = bias ? bias[colo] : 0.f;
  int row0 = by + ((lane >> 4) * 4);
#pragma unroll
  for (int mi = 0; mi < 4; mi++) {
#pragma unroll
    for (int j = 0; j < 4; j++) {
      int row = row0 + mi * 16 + j;
      float v = acc[mi][j] + bi;
      if (ACT == 1) v = fmaxf(v, 0.f);
      if (OUT_BF16)
        ((unsigned short*)Cout)[(size_t)row * ldc + colo] = f2bf(v);
      else
        ((float*)Cout)[partStride * part + (size_t)row * ldc + colo] = v;
    }
  }
}

// ---------------------------------------------------------------------------
// Fused GEMM (N=512, packed B) + residual + LayerNorm.
// Block = 64 rows x ALL 512 cols, 512 thr = 8 waves, wave = 64x64
// (acc[4][4]). Epilogue: +bias, +x residual, in-block LN over 512 cols,
// writes x (f32) and xbf (bf16). Rows < Msplit use B0/bias0/s0/b0ln.
// ---------------------------------------------------------------------------
__global__ __launch_bounds__(512, 2) void gemmpln_kernel(
    const unsigned short* __restrict__ A, int lda,
    const unsigned short* __restrict__ B0, const unsigned short* __restrict__ B1,
    const float* __restrict__ bias0, const float* __restrict__ bias1,
    float* __restrict__ x, unsigned short* __restrict__ xbf,
    const float* __restrict__ s0, const float* __restrict__ b0ln,
    const float* __restrict__ s1, const float* __restrict__ b1ln,
    int K, int Msplit) {
  __shared__ char AsB[64 * 128];       // 8 KB
  __shared__ float redS[64 * 8], redQ[64 * 8];
  __shared__ float smean[64], srstd[64];
  int tid = threadIdx.x;
  int by = blockIdx.x * 64;
  const unsigned short* Bp = (by < Msplit) ? B0 : B1;
  const float* bias = (by < Msplit) ? bias0 : bias1;
  const float* lns = (by < Msplit) ? s0 : s1;
  const float* lnb = (by < Msplit) ? b0ln : b1ln;
  int lane = tid & 63, w = tid >> 6;   // wave w -> cols w*64..w*64+63
  int ksteps = K >> 6;

  // A staging: row = tid>>3 (0..63), 8 shorts at ak = (tid&7)*8
  int arow = tid >> 3;
  int ak = (tid & 7) * 8;
  const unsigned short* Ap = A + (size_t)(by + arow) * lda + ak;
  int aswz = (arow & 7) << 4;
  char* As_w = AsB + arow * 128 + ((ak * 2) ^ aswz);

  int fswz = ((lane & 7) << 4);
  const char* As_rh0 = AsB + (lane & 15) * 128 + (((lane >> 4) * 32) ^ fswz);
  const char* As_rh1 = AsB + (lane & 15) * 128 + ((((lane >> 4) * 32) + 16) ^ fswz);

  // packed B col-groups w*4 + ni
  const unsigned short* Bl = Bp + ((size_t)(w * 4) * ksteps) * 1024 +
                             (size_t)lane * 8;

  f32x4 acc[4][4] = {};
  bf16x8 pa = *(const bf16x8*)(Ap);
  for (int ks = 0; ks < ksteps; ks++) {
    bf16x8 b0v[4], b1v[4];
#pragma unroll
    for (int ni = 0; ni < 4; ni++) {
      const unsigned short* p = Bl + ((size_t)ni * ksteps + ks) * 1024;
      b0v[ni] = *(const bf16x8*)(p);
      b1v[ni] = *(const bf16x8*)(p + 512);
    }
    __syncthreads();
    *(bf16x8*)As_w = pa;
    __syncthreads();
    if (ks + 1 < ksteps) pa = *(const bf16x8*)(Ap + (ks + 1) * 64);
#pragma unroll
    for (int mi = 0; mi < 4; mi++) {
      bf16x8 af0 = *(const bf16x8*)(As_rh0 + mi * 16 * 128);
      bf16x8 af1 = *(const bf16x8*)(As_rh1 + mi * 16 * 128);
#pragma unroll
      for (int ni = 0; ni < 4; ni++) {
        acc[mi][ni] = __builtin_amdgcn_mfma_f32_16x16x32_bf16(af0, b0v[ni], acc[mi][ni], 0, 0, 0);
        acc[mi][ni] = __builtin_amdgcn_mfma_f32_16x16x32_bf16(af1, b1v[ni], acc[mi][ni], 0, 0, 0);
      }
    }
  }

  // ---- epilogue: bias + residual, LN stats, transform, write ----
  int coll = w * 64 + (lane & 15);
  float bv[4], lsv[4], lbv[4];
#pragma unroll
  for (int ni = 0; ni < 4; ni++) {
    bv[ni] = bias ? bias[coll + ni * 16] : 0.f;
    lsv[ni] = lns[coll + ni * 16];
    lbv[ni] = lnb[coll + ni * 16];
  }
  int rbase = (lane >> 4) * 4;
#pragma unroll
  for (int mi = 0; mi < 4; mi++) {
#pragma unroll
    for (int j = 0; j < 4; j++) {
      int r = mi * 16 + rbase + j;
      size_t grow = (size_t)(by + r);
      float ps = 0.f, pq = 0.f;
#pragma unroll
      for (int ni = 0; ni < 4; ni++) {
        float v = acc[mi][ni][j] + bv[ni] + x[grow * HD + coll + ni * 16];
        acc[mi][ni][j] = v;
        ps += v;
        pq += v * v;
      }
      ps += __shfl_xor(ps, 1); pq += __shfl_xor(pq, 1);
      ps += __shfl_xor(ps, 2); pq += __shfl_xor(pq, 2);
      ps += __shfl_xor(ps, 4); pq += __shfl_xor(pq, 4);
      ps += __shfl_xor(ps, 8); pq += __shfl_xor(pq, 8);
      if ((lane & 15) == 0) {
        redS[r * 8 + w] = ps;
        redQ[r * 8 + w] = pq;
      }
    }
  }
  __syncthreads();
  {
    int r2 = tid >> 3, c2 = tid & 7;
    float sv = redS[r2 * 8 + c2], qv = redQ[r2 * 8 + c2];
    sv += __shfl_xor(sv, 1); qv += __shfl_xor(qv, 1);
    sv += __shfl_xor(sv, 2); qv += __shfl_xor(qv, 2);
    sv += __shfl_xor(sv, 4); qv += __shfl_xor(qv, 4);
    if (c2 == 0) {
      float mean = sv * (1.f / HD);
      float var = qv * (1.f / HD) - mean * mean;
      smean[r2] = mean;
      srstd[r2] = rsqrtf(var + 1e-5f);
    }
  }
  __syncthreads();
#pragma unroll
  for (int mi = 0; mi < 4; mi++) {
#pragma unroll
    for (int j = 0; j < 4; j++) {
      int r = mi * 16 + rbase + j;
      size_t grow = (size_t)(by + r);
      float mean = smean[r], rstd = srstd[r];
#pragma unroll
      for (int ni = 0; ni < 4; ni++) {
        int col = coll + ni * 16;
        float o = (acc[mi][ni][j] - mean) * rstd * lsv[ni] + lbv[ni];
        x[grow * HD + col] = o;
        xbf[grow * HD + col] = f2bf(o);
      }
    }
  }
}

// ---------------------------------------------------------------------------
// f32-input MFMA GEMM (fallback path).
// ---------------------------------------------------------------------------
template <int ACT, int OUT_BF16>
__global__ __launch_bounds__(256) void gemm64_kernel(
    const float* __restrict__ A, int lda,
    const float* __restrict__ B0, const float* __restrict__ B1, int ldb,
    const float* __restrict__ bias0, const float* __restrict__ bias1,
    void* __restrict__ Cout, int ldc, int N, int K, int Msplit) {
  __shared__ short As[64 * 72];
  __shared__ short Bs[64 * 72];
  int tid = threadIdx.x;
  int by = blockIdx.y * 64, bx = blockIdx.x * 64;
  const float* Bw = (by < Msplit) ? B0 : B1;
  const float* bias = (by < Msplit) ? bias0 : bias1;
  int lane = tid & 63, w = tid >> 6;
  int wr = w >> 1, wc = w & 1;
  int srow = tid >> 2, skq = (tid & 3) * 16;
  const float* Ap = A + (size_t)(by + srow) * lda + skq;
  const float* Bp = Bw + (size_t)(bx + srow) * ldb + skq;
  short* As_w = As + srow * 72 + skq;
  short* Bs_w = Bs + srow * 72 + skq;
  f32x4 acc[2][2] = {};
  const short* As_r = As + (wr * 32 + (lane & 15)) * 72 + ((lane >> 4) * 8);
  const short* Bs_r = Bs + (wc * 32 + (lane & 15)) * 72 + ((lane >> 4) * 8);
  float4 pa0 = *(const float4*)(Ap);
  float4 pa1 = *(const float4*)(Ap + 4);
  float4 pa2 = *(const float4*)(Ap + 8);
  float4 pa3 = *(const float4*)(Ap + 12);
  float4 pb0 = *(const float4*)(Bp);
  float4 pb1 = *(const float4*)(Bp + 4);
  float4 pb2 = *(const float4*)(Bp + 8);
  float4 pb3 = *(const float4*)(Bp + 12);
  for (int k0 = 0; k0 < K; k0 += 64) {
    __syncthreads();
    *(ushort4*)(As_w +  0) = ushort4{f2bf(pa0.x), f2bf(pa0.y), f2bf(pa0.z), f2bf(pa0.w)};
    *(ushort4*)(As_w +  4) = ushort4{f2bf(pa1.x), f2bf(pa1.y), f2bf(pa1.z), f2bf(pa1.w)};
    *(ushort4*)(As_w +  8) = ushort4{f2bf(pa2.x), f2bf(pa2.y), f2bf(pa2.z), f2bf(pa2.w)};
    *(ushort4*)(As_w + 12) = ushort4{f2bf(pa3.x), f2bf(pa3.y), f2bf(pa3.z), f2bf(pa3.w)};
    *(ushort4*)(Bs_w +  0) = ushort4{f2bf(pb0.x), f2bf(pb0.y), f2bf(pb0.z), f2bf(pb0.w)};
    *(ushort4*)(Bs_w +  4) = ushort4{f2bf(pb1.x), f2bf(pb1.y), f2bf(pb1.z), f2bf(pb1.w)};
    *(ushort4*)(Bs_w +  8) = ushort4{f2bf(pb2.x), f2bf(pb2.y), f2bf(pb2.z), f2bf(pb2.w)};
    *(ushort4*)(Bs_w + 12) = ushort4{f2bf(pb3.x), f2bf(pb3.y), f2bf(pb3.z), f2bf(pb3.w)};
    __syncthreads();
    if (k0 + 64 < K) {
      pa0 = *(const float4*)(Ap + k0 + 64);
      pa1 = *(const float4*)(Ap + k0 + 68);
      pa2 = *(const float4*)(Ap + k0 + 72);
      pa3 = *(const float4*)(Ap + k0 + 76);
      pb0 = *(const float4*)(Bp + k0 + 64);
      pb1 = *(const float4*)(Bp + k0 + 68);
      pb2 = *(const float4*)(Bp + k0 + 72);
      pb3 = *(const float4*)(Bp + k0 + 76);
    }
#pragma unroll
    for (int s = 0; s < 2; s++) {
      bf16x8 af0 = *(const bf16x8*)(As_r + s * 32);
      bf16x8 af1 = *(const bf16x8*)(As_r + s * 32 + 16 * 72);
      bf16x8 bg0 = *(const bf16x8*)(Bs_r + s * 32);
      bf16x8 bg1 = *(const bf16x8*)(Bs_r + s * 32 + 16 * 72);
      acc[0][0] = __builtin_amdgcn_mfma_f32_16x16x32_bf16(af0, bg0, acc[0][0], 0, 0, 0);
      acc[0][1] = __builtin_amdgcn_mfma_f32_16x16x32_bf16(af0, bg1, acc[0][1], 0, 0, 0);
      acc[1][0] = __builtin_amdgcn_mfma_f32_16x16x32_bf16(af1, bg0, acc[1][0], 0, 0, 0);
      acc[1][1] = __builtin_amdgcn_mfma_f32_16x16x32_bf16(af1, bg1, acc[1][1], 0, 0, 0);
    }
  }
  int col0 = bx + wc * 32 + (lane & 15);
  int row0 = by + wr * 32 + ((lane >> 4) * 4);
#pragma unroll
  for (int ni = 0; ni < 2; ni++) {
    int col = col0 + ni * 16;
    float bi = bias ? bias[col] : 0.f;
#pragma unroll
    for (int mi = 0; mi < 2; mi++) {
#pragma unroll
      for (int j = 0; j < 4; j++) {
        int row = row0 + mi * 16 + j;
        float v = acc[mi][ni][j] + bi;
        if (ACT == 1) v = fmaxf(v, 0.f);
        if (OUT_BF16)
          ((unsigned short*)Cout)[(size_t)row * ldc + col] = f2bf(v);
        else
          ((float*)Cout)[(size_t)row * ldc + col] = v;
      }
    }
  }
}

// ---------------------------------------------------------------------------
// Tiled attention body (32 q-rows per block), merged audio+label kernel.
// ---------------------------------------------------------------------------
template <int S, int OBF>
__device__ __forceinline__ void attn_body(
    const float* __restrict__ qkv, void* __restrict__ ctx, int rowbase, int q0,
    int h, float (*qs)[66], float* sc, float (*redm)[8], float (*redsum)[8]) {
  constexpr int KLEN = S / 8;
  const float* base = qkv + (size_t)rowbase * 1536;
  int tid = threadIdx.x;
  for (int i = tid; i < 512; i += 256) {
    int qi = i >> 4, d4 = (i & 15) * 4;
    float4 v = *(const float4*)(base + (size_t)(q0 + qi) * 1536 + h * 64 + d4);
    qs[qi][d4 + 0] = v.x; qs[qi][d4 + 1] = v.y;
    qs[qi][d4 + 2] = v.z; qs[qi][d4 + 3] = v.w;
  }
  __syncthreads();
  int qi = tid & 31, kg = tid >> 5;
  float sloc[KLEN];
  float m = -1e30f;
#pragma unroll
  for (int kk = 0; kk < KLEN; kk++) {
    int k = kg * KLEN + kk;
    const float4* kr = (const float4*)(base + (size_t)k * 1536 + 512 + h * 64);
    float acc = 0.f;
#pragma unroll
    for (int d = 0; d < 16; d++) {
      float4 kv = kr[d];
      acc += qs[qi][d * 4 + 0] * kv.x + qs[qi][d * 4 + 1] * kv.y +
             qs[qi][d * 4 + 2] * kv.z + qs[qi][d * 4 + 3] * kv.w;
    }
    acc *= 0.125f;
    sloc[kk] = acc;
    m = fmaxf(m, acc);
  }
  redm[qi][kg] = m;
  __syncthreads();
  float M = redm[qi][0];
#pragma unroll
  for (int g = 1; g < 8; g++) M = fmaxf(M, redm[qi][g]);
  float ssum = 0.f;
#pragma unroll
  for (int kk = 0; kk < KLEN; kk++) {
    float e = __expf(sloc[kk] - M);
    sc[qi * (S + 1) + kg * KLEN + kk] = e;
    ssum += e;
  }
  redsum[qi][kg] = ssum;
  __syncthreads();
  float sum = redsum[qi][0];
#pragma unroll
  for (int g = 1; g < 8; g++) sum += redsum[qi][g];
  float inv = 1.f / sum;
  int d0 = kg * 8;
  float a8[8] = {};
  for (int k = 0; k < S; k++) {
    float p = sc[qi * (S + 1) + k];
    const float4* vr = (const float4*)(base + (size_t)k * 1536 + 1024 + h * 64 + d0);
    float4 v0 = vr[0], v1 = vr[1];
    a8[0] += p * v0.x; a8[1] += p * v0.y; a8[2] += p * v0.z; a8[3] += p * v0.w;
    a8[4] += p * v1.x; a8[5] += p * v1.y; a8[6] += p * v1.z; a8[7] += p * v1.w;
  }
  size_t obase = ((size_t)(rowbase + q0 + qi)) * HD + h * 64 + d0;
#pragma unroll
  for (int j = 0; j < 8; j++) {
    float c = a8[j] * inv;
    if (OBF) ((unsigned short*)ctx)[obase + j] = f2bf(c);
    else     ((float*)ctx)[obase + j] = c;
  }
}

template <int OBF>
__global__ __launch_bounds__(256) void attn_merged_kernel(
    const float* __restrict__ qkv, void* __restrict__ ctx) {
  __shared__ float qs[32][66];
  __shared__ float sc[32 * 257];
  __shared__ float redm[32][8], redsum[32][8];
  int h = blockIdx.y, bb = blockIdx.z;
  if (blockIdx.x < 8)
    attn_body<256, OBF>(qkv, ctx, bb * 256, blockIdx.x * 32, h, qs, sc, redm, redsum);
  else
    attn_body<64, OBF>(qkv, ctx, 1024 + bb * 64, (blockIdx.x - 8) * 32, h, qs, sc,
                       redm, redsum);
}

// ---------------------------------------------------------------------------
// Residual add + LayerNorm (two-part); sums nparts partials of y (fallback).
// ---------------------------------------------------------------------------
__global__ __launch_bounds__(256) void add_ln_kernel(
    float* __restrict__ x, const float* __restrict__ y, int nparts,
    size_t pstride,
    const float* __restrict__ s0, const float* __restrict__ b0,
    const float* __restrict__ s1, const float* __restrict__ b1,
    unsigned short* __restrict__ xbf) {
  int row = blockIdx.x, tid = threadIdx.x;
  const float* s = (row < 1024) ? s0 : s1;
  const float* bsh = (row < 1024) ? b0 : b1;
  float* xr = x + (size_t)row * HD;
  float v0 = xr[tid];
  float v1 = xr[tid + 256];
  for (int p = 0; p < nparts; p++) {
    const float* yr = y + p * pstride + (size_t)row * HD;
    v0 += yr[tid];
    v1 += yr[tid + 256];
  }
  __shared__ float rs_[256], rq_[256];
  rs_[tid] = v0 + v1;
  rq_[tid] = v0 * v0 + v1 * v1;
  __syncthreads();
  for (int st = 128; st > 0; st >>= 1) {
    if (tid < st) { rs_[tid] += rs_[tid + st]; rq_[tid] += rq_[tid + st]; }
    __syncthreads();
  }
  float mean = rs_[0] * (1.f / HD);
  float var = rq_[0] * (1.f / HD) - mean * mean;
  float rstd = rsqrtf(var + 1e-5f);
  float o0 = (v0 - mean) * rstd * s[tid] + bsh[tid];
  float o1 = (v1 - mean) * rstd * s[tid + 256] + bsh[tid + 256];
  xr[tid] = o0;
  xr[tid + 256] = o1;
  if (xbf) {
    xbf[(size_t)row * HD + tid] = f2bf(o0);
    xbf[(size_t)row * HD + tid + 256] = f2bf(o1);
  }
}

// ---------------------------------------------------------------------------
// Joint v9: 128x512 blocks, 8 waves of 64x128, acc[4][8], f32 inputs,
// v_cvt_pk_bf16_f32 packing, 2-pass LSE via partials + finish kernel.
// ---------------------------------------------------------------------------
__global__ __launch_bounds__(512, 2) void joint_fused_kernel(
    const float* __restrict__ ha,  // [B*T,2048] f32
    const float* __restrict__ hl,  // [B*U,2048] f32
    const unsigned short* __restrict__ W, const float* __restrict__ wb,
    float* __restrict__ out, float* __restrict__ pmax, float* __restrict__ psum) {
  __shared__ char AsB[128 * 128];
  __shared__ float redm[128 * 4];
  __shared__ float reds[128 * 4];
  int tid = threadIdx.x;
  int colblk = blockIdx.x;
  int m0 = blockIdx.y * 128;
  int b = m0 >> 14;
  int lane = tid & 63, w = tid >> 6;
  int wave_r = w >> 2, wc2 = w & 3;

  int arow = tid >> 2;
  int ak = (tid & 3) * 16;
  int bt = (m0 + arow) >> 6;
  int u_s = arow & 63;
  const float* ha_p = ha + (size_t)bt * KJOINT + ak;
  const float* hl_p = hl + (size_t)(b * 64 + u_s) * KJOINT + ak;
  int aswz = (arow & 7) << 4;
  char* As_w0 = AsB + arow * 128 + ((ak * 2) ^ aswz);
  char* As_w1 = AsB + arow * 128 + (((ak * 2) + 16) ^ aswz);

  int frow = wave_r * 64 + (lane & 15);
  int fswz = ((lane & 7) << 4);
  const char* As_rh0 = AsB + frow * 128 + (((lane >> 4) * 32) ^ fswz);
  const char* As_rh1 = AsB + frow * 128 + ((((lane >> 4) * 32) + 16) ^ fswz);

  const unsigned short* Wl = W + ((size_t)(colblk * 32 + wc2 * 8) * 32) * 1024 +
                             (size_t)lane * 8;

  f32x4 acc[4][8] = {};
  for (int k0 = 0; k0 < KJOINT; k0 += 64) {
    int ksoff = (k0 >> 6) * 1024;
    bf16x8 b0[8], b1[8];
#pragma unroll
    for (int ni = 0; ni < 8; ni++) {
      const unsigned short* p = Wl + (size_t)ni * 32768 + ksoff;
      b0[ni] = *(const bf16x8*)(p);
      b1[ni] = *(const bf16x8*)(p + 512);
    }
    float4 a0 = *(const float4*)(ha_p + k0);
    float4 a1 = *(const float4*)(ha_p + k0 + 4);
    float4 a2 = *(const float4*)(ha_p + k0 + 8);
    float4 a3 = *(const float4*)(ha_p + k0 + 12);
    float4 l0 = *(const float4*)(hl_p + k0);
    float4 l1 = *(const float4*)(hl_p + k0 + 4);
    float4 l2 = *(const float4*)(hl_p + k0 + 8);
    float4 l3 = *(const float4*)(hl_p + k0 + 12);
    float t[16];
    t[0] = fast_tanh(a0.x + l0.x);  t[1] = fast_tanh(a0.y + l0.y);
    t[2] = fast_tanh(a0.z + l0.z);  t[3] = fast_tanh(a0.w + l0.w);
    t[4] = fast_tanh(a1.x + l1.x);  t[5] = fast_tanh(a1.y + l1.y);
    t[6] = fast_tanh(a1.z + l1.z);  t[7] = fast_tanh(a1.w + l1.w);
    t[8] = fast_tanh(a2.x + l2.x);  t[9] = fast_tanh(a2.y + l2.y);
    t[10] = fast_tanh(a2.z + l2.z); t[11] = fast_tanh(a2.w + l2.w);
    t[12] = fast_tanh(a3.x + l3.x); t[13] = fast_tanh(a3.y + l3.y);
    t[14] = fast_tanh(a3.z + l3.z); t[15] = fast_tanh(a3.w + l3.w);
    unsigned pk0[4], pk1[4];
#pragma unroll
    for (int p = 0; p < 4; p++) {
      asm("v_cvt_pk_bf16_f32 %0, %1, %2"
          : "=v"(pk0[p]) : "v"(t[2 * p]), "v"(t[2 * p + 1]));
      asm("v_cvt_pk_bf16_f32 %0, %1, %2"
          : "=v"(pk1[p]) : "v"(t[8 + 2 * p]), "v"(t[9 + 2 * p]));
    }
    __syncthreads();
    *(bf16x8*)As_w0 = *(const bf16x8*)pk0;
    *(bf16x8*)As_w1 = *(const bf16x8*)pk1;
    __syncthreads();
#pragma unroll
    for (int mi = 0; mi < 4; mi++) {
      bf16x8 af = *(const bf16x8*)(As_rh0 + mi * 16 * 128);
#pragma unroll
      for (int ni = 0; ni < 8; ni++)
        acc[mi][ni] = __builtin_amdgcn_mfma_f32_16x16x32_bf16(
            af, b0[ni], acc[mi][ni], 0, 0, 0);
    }
#pragma unroll
    for (int mi = 0; mi < 4; mi++) {
      bf16x8 af = *(const bf16x8*)(As_rh1 + mi * 16 * 128);
#pragma unroll
      for (int ni = 0; ni < 8; ni++)
        acc[mi][ni] = __builtin_amdgcn_mfma_f32_16x16x32_bf16(
            af, b1[ni], acc[mi][ni], 0, 0, 0);
    }
  }

  int coll = colblk * 512 + wc2 * 128 + (lane & 15);
  float bv[8];
#pragma unroll
  for (int ni = 0; ni < 8; ni++) bv[ni] = wb[coll + ni * 16];
#pragma unroll
  for (int mi = 0; mi < 4; mi++)
#pragma unroll
    for (int ni = 0; ni < 8; ni++)
#pragma unroll
      for (int j = 0; j < 4; j++) acc[mi][ni][j] += bv[ni];

  int rbase = wave_r * 64 + ((lane >> 4) * 4);
  float rmax[4][4], rsum[4][4];
#pragma unroll
  for (int mi = 0; mi < 4; mi++) {
#pragma unroll
    for (int j = 0; j < 4; j++) {
      float m = acc[mi][0][j];
#pragma unroll
      for (int ni = 1; ni < 8; ni++) m = fmaxf(m, acc[mi][ni][j]);
      m = fmaxf(m, __shfl_xor(m, 1));
      m = fmaxf(m, __shfl_xor(m, 2));
      m = fmaxf(m, __shfl_xor(m, 4));
      m = fmaxf(m, __shfl_xor(m, 8));
      rmax[mi][j] = m;
      float s = 0.f;
#pragma unroll
      for (int ni = 0; ni < 8; ni++) s += __expf(acc[mi][ni][j] - m);
      s += __shfl_xor(s, 1);
      s += __shfl_xor(s, 2);
      s += __shfl_xor(s, 4);
      s += __shfl_xor(s, 8);
      rsum[mi][j] = s;
    }
  }
  if ((lane & 15) == 0) {
#pragma unroll
    for (int mi = 0; mi < 4; mi++)
#pragma unroll
      for (int j = 0; j < 4; j++) {
        redm[(rbase + mi * 16 + j) * 4 + wc2] = rmax[mi][j];
        reds[(rbase + mi * 16 + j) * 4 + wc2] = rsum[mi][j];
      }
  }
  __syncthreads();
  {
    int r2 = tid >> 2, c2 = tid & 3;
    float m = redm[r2 * 4 + c2];
    float M = fmaxf(m, __shfl_xor(m, 1));
    M = fmaxf(M, __shfl_xor(M, 2));
    float s = reds[r2 * 4 + c2] * __expf(m - M);
    s += __shfl_xor(s, 1);
    s += __shfl_xor(s, 2);
    if (c2 == 0) {
      pmax[(size_t)(m0 + r2) * 2 + colblk] = M;
      psum[(size_t)(m0 + r2) * 2 + colblk] = s;
    }
  }
#pragma unroll
  for (int mi = 0; mi < 4; mi++) {
#pragma unroll
    for (int j = 0; j < 4; j++) {
      size_t row = (size_t)m0 + rbase + mi * 16 + j;
#pragma unroll
      for (int ni = 0; ni < 8; ni++)
        out[row * VOUT + coll + ni * 16] = acc[mi][ni][j];
    }
  }
}

__global__ __launch_bounds__(256) void lse_finish_kernel(
    float* __restrict__ out, const float* __restrict__ pmax,
    const float* __restrict__ psum) {
  int r0 = blockIdx.x * 32;
  int tid = threadIdx.x;
  for (int i = 0; i < 32; i++) {
    int r = r0 + i;
    float m0 = pmax[(size_t)r * 2], m1 = pmax[(size_t)r * 2 + 1];
    float M = fmaxf(m0, m1);
    float S = psum[(size_t)r * 2] * __expf(m0 - M) +
              psum[(size_t)r * 2 + 1] * __expf(m1 - M);
    float lse = M + __logf(S);
    float4* p = (float4*)(out + (size_t)r * VOUT) + tid;
    float4 v = *p;
    v.x -= lse; v.y -= lse; v.z -= lse; v.w -= lse;
    *p = v;
  }
}

// ---------------------------------------------------------------------------
// Host side
// ---------------------------------------------------------------------------
extern "C" void kernel_launch(void* const* d_in, const int* in_sizes, int n_in,
                              void* d_out, int out_size, void* d_ws, size_t ws_size,
                              hipStream_t stream) {
  const int B = 4, T = 256, U = 64;
  const float* input_values = (const float*)d_in[0];
  const int* labels = (const int*)d_in[1];
  const float* a_lin_w = (const float*)d_in[4];
  const float* a_lin_b = (const float*)d_in[5];
  const float* a_pos = (const float*)d_in[6];
  const float* l_word = (const float*)d_in[7];
  const float* l_pos = (const float*)d_in[8];
  const float* joint_w = (const float*)d_in[9];
  const float* joint_b = (const float*)d_in[10];
  const float* out_w = (const float*)d_in[11];
  const float* out_b = (const float*)d_in[12];

  const float* a_qkv_w = (const float*)d_in[13];
  const float* a_qkv_b = (const float*)d_in[14];
  const float* a_out_w = (const float*)d_in[15];
  const float* a_out_b = (const float*)d_in[16];
  const float* a_ff1_w = (const float*)d_in[17];
  const float* a_ff1_b = (const float*)d_in[18];
  const float* a_ff2_w = (const float*)d_in[19];
  const float* a_ff2_b = (const float*)d_in[20];
  const float* a_ln1_s = (const float*)d_in[21];
  const float* a_ln1_b = (const float*)d_in[22];
  const float* a_ln2_s = (const float*)d_in[23];
  const float* a_ln2_b = (const float*)d_in[24];
  const float* l_qkv_w = (const float*)d_in[25];
  const float* l_qkv_b = (const float*)d_in[26];
  const float* l_out_w = (const float*)d_in[27];
  const float* l_out_b = (const float*)d_in[28];
  const float* l_ff1_w = (const float*)d_in[29];
  const float* l_ff1_b = (const float*)d_in[30];
  const float* l_ff2_w = (const float*)d_in[31];
  const float* l_ff2_b = (const float*)d_in[32];
  const float* l_ln1_s = (const float*)d_in[33];
  const float* l_ln1_b = (const float*)d_in[34];
  const float* l_ln2_s = (const float*)d_in[35];
  const float* l_ln2_b = (const float*)d_in[36];

  float* ws = (float*)d_ws;
  float* x_all = ws;                       // 655360
  float* qkv   = x_all + 655360;           // 1966080
  float* tmp   = qkv + 1966080;            // 2621440
  float* pmax  = tmp + 2621440;            // 131072
  float* psum  = pmax + 131072;            // 131072
  size_t off = 5505024;

  unsigned short* x_bf   = (unsigned short*)(ws + off);            // 327680 f
  unsigned short* ctx_bf = (unsigned short*)(ws + off + 327680);   // 327680 f
  unsigned short* ff1_bf = (unsigned short*)(ws + off + 655360);   // 1310720 f
  unsigned short* Wb     = (unsigned short*)(ws + off + 3276800);  // 1048576 f
  size_t woff = off + 4325376;
  unsigned short* a_qkv_wb = (unsigned short*)(ws + woff);               // 4718592 f
  unsigned short* a_out_wb = (unsigned short*)(ws + woff + 4718592);     // 1572864 f
  unsigned short* a_ff1_wb = (unsigned short*)(ws + woff + 6291456);     // 6291456 f
  unsigned short* a_ff2_wb = (unsigned short*)(ws + woff + 12582912);    // 6291456 f
  unsigned short* l_qkv_wb = (unsigned short*)(ws + woff + 18874368);    // 1572864 f
  unsigned short* l_out_wb = (unsigned short*)(ws + woff + 20447232);    // 524288 f
  unsigned short* l_ff1_wb = (unsigned short*)(ws + woff + 20971520);    // 2097152 f
  unsigned short* l_ff2_wb = (unsigned short*)(ws + woff + 23068672);    // 2097152 f
  unsigned short* Wa_pk    = (unsigned short*)(ws + woff + 25165824);    // 524288 f
  unsigned short* Wl_pk    = (unsigned short*)(ws + woff + 25690112);    // 524288 f
  float* hj = ws + woff + 26214400;        // 1280*2048 = 2621440 f (ha|hl f32)
  size_t need_floats = woff + 26214400 + 2621440;
  bool fast = ws_size >= need_floats * sizeof(float);

  if (fast) {
    // ---- one merged pack dispatch ----
    PackArgs pa;
    pa.s[0]  = {a_qkv_w,        a_qkv_wb, 512,  512,  12 * 1536 * 512 / 8};
    pa.s[1]  = {a_out_w,        a_out_wb, 512,  512,  12 * 512 * 512 / 8};
    pa.s[2]  = {a_ff1_w,        a_ff1_wb, 512,  512,  12 * 2048 * 512 / 8};
    pa.s[3]  = {a_ff2_w,        a_ff2_wb, 2048, 2048, 12 * 512 * 2048 / 8};
    pa.s[4]  = {l_qkv_w,        l_qkv_wb, 512,  512,  4 * 1536 * 512 / 8};
    pa.s[5]  = {l_out_w,        l_out_wb, 512,  512,  4 * 512 * 512 / 8};
    pa.s[6]  = {l_ff1_w,        l_ff1_wb, 512,  512,  4 * 2048 * 512 / 8};
    pa.s[7]  = {l_ff2_w,        l_ff2_wb, 2048, 2048, 4 * 512 * 2048 / 8};
    pa.s[8]  = {joint_w,        Wa_pk,    1024, 512,  2048 * 512 / 8};
    pa.s[9]  = {joint_w + 512,  Wl_pk,    1024, 512,  2048 * 512 / 8};
    pa.s[10] = {out_w,          Wb,       2048, 2048, 1024 * 2048 / 8};
    int tot8 = 0;
    for (int i = 0; i < 11; i++) tot8 += pa.s[i].nel8;
    pack_all_kernel<<<tot8 / 256, 256, 0, stream>>>(pa);

    // ---- merged embeddings ----
    embed_all_kernel<<<1280, 256, 0, stream>>>(
        input_values, a_lin_w, a_lin_b, a_pos, labels, l_word, l_pos,
        x_all, x_bf);

    // ---- merged encoder layers (5 dispatches each) ----
    for (int l = 0; l < 12; l++) {
      bool both = (l < 4);
      int M = both ? 1280 : 1024;
      int gy = M / 64;
      const unsigned short* qw1 = both ? l_qkv_wb + (size_t)l * 1536 * HD : a_qkv_wb;
      const float* qb1 = both ? l_qkv_b + (size_t)l * 1536 : a_qkv_b;
      const unsigned short* ow1 = both ? l_out_wb + (size_t)l * HD * HD : a_out_wb;
      const float* ob1 = both ? l_out_b + (size_t)l * HD : a_out_b;
      const unsigned short* f1w1 = both ? l_ff1_wb + (size_t)l * FF * HD : a_ff1_wb;
      const float* f1b1 = both ? l_ff1_b + (size_t)l * FF : a_ff1_b;
      const unsigned short* f2w1 = both ? l_ff2_wb + (size_t)l * HD * FF : a_ff2_wb;
      const float* f2b1 = both ? l_ff2_b + (size_t)l * HD : a_ff2_b;
      const float* n1s1 = both ? l_ln1_s + (size_t)l * HD : a_ln1_s;
      const float* n1b1 = both ? l_ln1_b + (size_t)l * HD : a_ln1_b;
      const float* n2s1 = both ? l_ln2_s + (size_t)l * HD : a_ln2_s;
      const float* n2b1 = both ? l_ln2_b + (size_t)l * HD : a_ln2_b;

      gemmp_kernel<0, 0><<<dim3(1536 / 64, gy, 1), 256, 0, stream>>>(
          x_bf, HD, a_qkv_wb + (size_t)l * 1536 * HD, qw1,
          a_qkv_b + (size_t)l * 1536, qb1, qkv, 1536, HD, 1024, 8, 0);
      attn_merged_kernel<1><<<dim3(both ? 10 : 8, 8, B), 256, 0, stream>>>(
          qkv, ctx_bf);
      gemmpln_kernel<<<gy, 512, 0, stream>>>(
          ctx_bf, HD, a_out_wb + (size_t)l * HD * HD, ow1,
          a_out_b + (size_t)l * HD, ob1, x_all, x_bf,
          a_ln1_s + (size_t)l * HD, a_ln1_b + (size_t)l * HD, n1s1, n1b1,
          HD, 1024);
      gemmp_kernel<1, 1><<<dim3(FF / 64, gy, 1), 256, 0, stream>>>(
          x_bf, HD, a_ff1_wb + (size_t)l * FF * HD, f1w1,
          a_ff1_b + (size_t)l * FF, f1b1, ff1_bf, FF, HD, 1024, 8, 0);
      gemmpln_kernel<<<gy, 512, 0, stream>>>(
          ff1_bf, FF, a_ff2_wb + (size_t)l * HD * FF, f2w1,
          a_ff2_b + (size_t)l * HD, f2b1, x_all, x_bf,
          a_ln2_s + (size_t)l * HD, a_ln2_b + (size_t)l * HD, n2s1, n2b1,
          FF, 1024);
    }

    // ---- joint projections -> f32 (one dispatch, Msplit row-switch) ----
    gemmp_kernel<0, 0><<<dim3(KJOINT / 64, 1280 / 64, 1), 256, 0, stream>>>(
        x_bf, HD, Wa_pk, Wl_pk, nullptr, joint_b, hj, KJOINT, HD, 1024, 8, 0);

    joint_fused_kernel<<<dim3(2, 512), 512, 0, stream>>>(
        hj, hj + (size_t)1024 * KJOINT, Wb, out_b, (float*)d_out, pmax, psum);
    lse_finish_kernel<<<(B * T * U) / 32, 256, 0, stream>>>(
        (float*)d_out, pmax, psum);
  } else {
    // ---- fallback: f32-staging path (small workspace) ----
    float* ctx = ws + off;                 // 655360
    float* ff1 = ctx + 655360;             // 2621440 (reused as hj2 after enc)
    float* hj2 = ff1;
    unsigned short* Wb2 = (unsigned short*)(qkv + 1310720);

    embed_all_kernel<<<1280, 256, 0, stream>>>(
        input_values, a_lin_w, a_lin_b, a_pos, labels, l_word, l_pos,
        x_all, nullptr);

    for (int l = 0; l < 12; l++) {
      bool both = (l < 4);
      int M = both ? 1280 : 1024;
      int gy = M / 64;
      const float* qw1 = both ? l_qkv_w + (size_t)l * 1536 * HD : a_qkv_w;
      const float* qb1 = both ? l_qkv_b + (size_t)l * 1536 : a_qkv_b;
      const float* ow1 = both ? l_out_w + (size_t)l * HD * HD : a_out_w;
      const float* ob1 = both ? l_out_b + (size_t)l * HD : a_out_b;
      const float* f1w1 = both ? l_ff1_w + (size_t)l * FF * HD : a_ff1_w;
      const float* f1b1 = both ? l_ff1_b + (size_t)l * FF : a_ff1_b;
      const float* f2w1 = both ? l_ff2_w + (size_t)l * HD * FF : a_ff2_w;
      const float* f2b1 = both ? l_ff2_b + (size_t)l * HD : a_ff2_b;
      const float* n1s1 = both ? l_ln1_s + (size_t)l * HD : a_ln1_s;
      const float* n1b1 = both ? l_ln1_b + (size_t)l * HD : a_ln1_b;
      const float* n2s1 = both ? l_ln2_s + (size_t)l * HD : a_ln2_s;
      const float* n2b1 = both ? l_ln2_b + (size_t)l * HD : a_ln2_b;

      gemm64_kernel<0, 0><<<dim3(1536 / 64, gy), 256, 0, stream>>>(
          x_all, HD, a_qkv_w + (size_t)l * 1536 * HD, qw1, HD,
          a_qkv_b + (size_t)l * 1536, qb1, qkv, 1536, 1536, HD, 1024);
      attn_merged_kernel<0><<<dim3(both ? 10 : 8, 8, B), 256, 0, stream>>>(
          qkv, ctx);
      gemm64_kernel<0, 0><<<dim3(HD / 64, gy), 256, 0, stream>>>(
          ctx, HD, a_out_w + (size_t)l * HD * HD, ow1, HD,
          a_out_b + (size_t)l * HD, ob1, tmp, HD, HD, HD, 1024);
      add_ln_kernel<<<M, 256, 0, stream>>>(x_all, tmp, 1, 0,
          a_ln1_s + (size_t)l * HD, a_ln1_b + (size_t)l * HD, n1s1, n1b1, nullptr);
      gemm64_kernel<1, 0><<<dim3(FF / 64, gy), 256, 0, stream>>>(
          x_all, HD, a_ff1_w + (size_t)l * FF * HD, f1w1, HD,
          a_ff1_b + (size_t)l * FF, f1b1, ff1, FF, FF, HD, 1024);
      gemm64_kernel<0, 0><<<dim3(HD / 64, gy), 256, 0, stream>>>(
          ff1, FF, a_ff2_w + (size_t)l * HD * FF, f2w1, FF,
          a_ff2_b + (size_t)l * HD, f2b1, tmp, HD, HD, FF, 1024);
      add_ln_kernel<<<M, 256, 0, stream>>>(x_all, tmp, 1, 0,
          a_ln2_s + (size_t)l * HD, a_ln2_b + (size_t)l * HD, n2s1, n2b1, nullptr);
    }

    pack_w_kernel<<<1024 * 2048 / 2048, 256, 0, stream>>>(out_w, 2048, 2048, Wb2);
    gemm64_kernel<0, 0><<<dim3(KJOINT / 64, 1280 / 64), 256, 0, stream>>>(
        x_all, HD, joint_w, joint_w + 512, 1024, nullptr, joint_b,
        hj2, KJOINT, KJOINT, HD, 1024);

    joint_fused_kernel<<<dim3(2, 512), 512, 0, stream>>>(
        hj2, hj2 + (size_t)1024 * KJOINT, Wb2, out_b, (float*)d_out, pmax, psum);
    lse_finish_kernel<<<(B * T * U) / 32, 256, 0, stream>>>(
        (float*)d_out, pmax, psum);
  }
}

// Round 18
// 1601.914 us; speedup vs baseline: 1.3674x; 1.3674x over previous
//
#include <hip/hip_runtime.h>
#include <cstddef>

#define HD 512
#define FF 2048
#define VOUT 1024
#define KJOINT 2048

typedef short bf16x8 __attribute__((ext_vector_type(8)));
typedef float f32x4 __attribute__((ext_vector_type(4)));

__device__ inline unsigned short f2bf(float f) {
  union { float f; unsigned u; } c{f};
  unsigned r = c.u + 0x7FFFu + ((c.u >> 16) & 1u);
  return (unsigned short)(r >> 16);
}
__device__ inline float bf2f(unsigned short h) {
  union { unsigned u; float f; } c{(unsigned)h << 16};
  return c.f;
}
__device__ inline float fast_tanh(float x) {
  float e = __expf(2.f * x);
  return 1.f - 2.f / (e + 1.f);
}

// ---------------------------------------------------------------------------
// Embedding kernels (write f32 x and optional bf16 mirror)
// ---------------------------------------------------------------------------
__global__ __launch_bounds__(256) void embed_audio_kernel(
    const float* __restrict__ inp, const float* __restrict__ w,
    const float* __restrict__ bias, const float* __restrict__ pos,
    float* __restrict__ x, unsigned short* __restrict__ xbf, int T) {
  int bt = blockIdx.x;
  int b = bt / T, t = bt - b * T;
  int tid = threadIdx.x;
  __shared__ __align__(16) float col[80];
  if (tid < 80) col[tid] = inp[((size_t)b * 80 + tid) * T + t];
  __syncthreads();
  for (int h = tid; h < HD; h += 256) {
    const float* wr = w + (size_t)h * 80;
    float acc = 0.f;
#pragma unroll
    for (int c = 0; c < 80; c++) acc += col[c] * wr[c];
    float v = acc + bias[h] + pos[(size_t)t * HD + h];
    x[(size_t)bt * HD + h] = v;
    if (xbf) xbf[(size_t)bt * HD + h] = f2bf(v);
  }
}

__global__ __launch_bounds__(256) void embed_label_kernel(
    const int* __restrict__ labels, const float* __restrict__ word,
    const float* __restrict__ pos, float* __restrict__ y,
    unsigned short* __restrict__ ybf, int U) {
  int bu = blockIdx.x;
  int u = bu % U;
  int tid = threadIdx.x;
  int id = labels[bu];
  for (int h = tid; h < HD; h += 256) {
    float v = word[(size_t)id * HD + h] + pos[(size_t)u * HD + h];
    y[(size_t)bu * HD + h] = v;
    if (ybf) ybf[(size_t)bu * HD + h] = f2bf(v);
  }
}

// ---------------------------------------------------------------------------
// Generalized weight pack: [N rows, K] f32 (row stride ld) -> bf16 fragment
// order dst[(colg*(K/64)+kstep)*1024 + chunk*512 + lane*8 + j].
// ---------------------------------------------------------------------------
__global__ __launch_bounds__(256) void pack_w_kernel(
    const float* __restrict__ in, int ld, int K,
    unsigned short* __restrict__ out) {
  int g = blockIdx.x * 256 + threadIdx.x;
  int kb = K >> 3;
  int col = g / kb;
  int k8 = g - col * kb;
  const float* src = in + (size_t)col * ld + k8 * 8;
  float4 v0 = *(const float4*)(src);
  float4 v1 = *(const float4*)(src + 4);
  int colg = col >> 4, cl = col & 15;
  int kstep = k8 >> 3;
  int lgrp = (k8 & 7) >> 1;
  int chunk = k8 & 1;
  int lane = lgrp * 16 + cl;
  unsigned short* dst =
      out + ((size_t)(colg * (K >> 6) + kstep)) * 1024 + chunk * 512 + lane * 8;
  *(ushort4*)(dst) = ushort4{f2bf(v0.x), f2bf(v0.y), f2bf(v0.z), f2bf(v0.w)};
  *(ushort4*)(dst + 4) = ushort4{f2bf(v1.x), f2bf(v1.y), f2bf(v1.z), f2bf(v1.w)};
}

// ---------------------------------------------------------------------------
// Packed-B bf16 GEMM with optional split-K (part = blockIdx.z):
// tile 64 rows x 64 cols, 256 thr = 4 waves, wave = 64x16 cols.
// B direct global->VGPR (contiguous 1KB wave-reads). A staged in 8KB
// swizzled LDS. Part p handles ksn ksteps starting at p*ksn; partial C
// (f32) written at Cout + p*partStride; bias added by part 0 only.
// ---------------------------------------------------------------------------
template <int ACT, int OUT_BF16>
__global__ __launch_bounds__(256) void gemmp_kernel(
    const unsigned short* __restrict__ A, int lda,
    const unsigned short* __restrict__ B0, const unsigned short* __restrict__ B1,
    const float* __restrict__ bias0, const float* __restrict__ bias1,
    void* __restrict__ Cout, int ldc, int K, int Msplit,
    int ksn, size_t partStride) {
  __shared__ char AsB[64 * 128];  // 8 KB
  int tid = threadIdx.x;
  int by = blockIdx.y * 64, bx = blockIdx.x * 64;
  int part = blockIdx.z;
  const unsigned short* Bp = (by < Msplit) ? B0 : B1;
  const float* bias = (by < Msplit) ? bias0 : bias1;
  if (part != 0) bias = nullptr;
  int lane = tid & 63, w = tid >> 6;
  int ksteps = K >> 6;
  int ks0 = part * ksn;
  int ksend = ks0 + ksn;

  int arow = tid >> 2;
  int ak = (tid & 3) * 16;
  const unsigned short* Ap = A + (size_t)(by + arow) * lda + ak;
  int aswz = (arow & 7) << 4;
  char* As_w0 = AsB + arow * 128 + ((ak * 2) ^ aswz);
  char* As_w1 = AsB + arow * 128 + (((ak * 2) + 16) ^ aswz);

  int fswz = ((lane & 7) << 4);
  const char* As_rh0 = AsB + (lane & 15) * 128 + (((lane >> 4) * 32) ^ fswz);
  const char* As_rh1 = AsB + (lane & 15) * 128 + ((((lane >> 4) * 32) + 16) ^ fswz);

  int cg = (bx >> 4) + w;
  const unsigned short* Bl = Bp + ((size_t)cg * ksteps) * 1024 + lane * 8;

  f32x4 acc[4] = {};
  bf16x8 pa0 = *(const bf16x8*)(Ap + ks0 * 64);
  bf16x8 pa1 = *(const bf16x8*)(Ap + ks0 * 64 + 8);
  for (int ks = ks0; ks < ksend; ks++) {
    const unsigned short* bp = Bl + (size_t)ks * 1024;
    bf16x8 b0 = *(const bf16x8*)(bp);
    bf16x8 b1 = *(const bf16x8*)(bp + 512);
    __syncthreads();
    *(bf16x8*)As_w0 = pa0;
    *(bf16x8*)As_w1 = pa1;
    __syncthreads();
    if (ks + 1 < ksend) {
      pa0 = *(const bf16x8*)(Ap + (ks + 1) * 64);
      pa1 = *(const bf16x8*)(Ap + (ks + 1) * 64 + 8);
    }
#pragma unroll
    for (int mi = 0; mi < 4; mi++) {
      bf16x8 af0 = *(const bf16x8*)(As_rh0 + mi * 16 * 128);
      bf16x8 af1 = *(const bf16x8*)(As_rh1 + mi * 16 * 128);
      acc[mi] = __builtin_amdgcn_mfma_f32_16x16x32_bf16(af0, b0, acc[mi], 0, 0, 0);
      acc[mi] = __builtin_amdgcn_mfma_f32_16x16x32_bf16(af1, b1, acc[mi], 0, 0, 0);
    }
  }
  int colo = bx + w * 16 + (lane & 15);
  float bi = bias ? bias[colo] : 0.f;
  int row0 = by + ((lane >> 4) * 4);
#pragma unroll
  for (int mi = 0; mi < 4; mi++) {
#pragma unroll
    for (int j = 0; j < 4; j++) {
      int row = row0 + mi * 16 + j;
      float v = acc[mi][j] + bi;
      if (ACT == 1) v = fmaxf(v, 0.f);
      if (OUT_BF16)
        ((unsigned short*)Cout)[(size_t)row * ldc + colo] = f2bf(v);
      else
        ((float*)Cout)[partStride * part + (size_t)row * ldc + colo] = v;
    }
  }
}

// ---------------------------------------------------------------------------
// f32-input MFMA GEMM (fallback path).
// ---------------------------------------------------------------------------
template <int ACT, int OUT_BF16>
__global__ __launch_bounds__(256) void gemm64_kernel(
    const float* __restrict__ A, int lda,
    const float* __restrict__ B0, const float* __restrict__ B1, int ldb,
    const float* __restrict__ bias0, const float* __restrict__ bias1,
    void* __restrict__ Cout, int ldc, int N, int K, int Msplit) {
  __shared__ short As[64 * 72];
  __shared__ short Bs[64 * 72];
  int tid = threadIdx.x;
  int by = blockIdx.y * 64, bx = blockIdx.x * 64;
  const float* Bw = (by < Msplit) ? B0 : B1;
  const float* bias = (by < Msplit) ? bias0 : bias1;
  int lane = tid & 63, w = tid >> 6;
  int wr = w >> 1, wc = w & 1;
  int srow = tid >> 2, skq = (tid & 3) * 16;
  const float* Ap = A + (size_t)(by + srow) * lda + skq;
  const float* Bp = Bw + (size_t)(bx + srow) * ldb + skq;
  short* As_w = As + srow * 72 + skq;
  short* Bs_w = Bs + srow * 72 + skq;
  f32x4 acc[2][2] = {};
  const short* As_r = As + (wr * 32 + (lane & 15)) * 72 + ((lane >> 4) * 8);
  const short* Bs_r = Bs + (wc * 32 + (lane & 15)) * 72 + ((lane >> 4) * 8);
  float4 pa0 = *(const float4*)(Ap);
  float4 pa1 = *(const float4*)(Ap + 4);
  float4 pa2 = *(const float4*)(Ap + 8);
  float4 pa3 = *(const float4*)(Ap + 12);
  float4 pb0 = *(const float4*)(Bp);
  float4 pb1 = *(const float4*)(Bp + 4);
  float4 pb2 = *(const float4*)(Bp + 8);
  float4 pb3 = *(const float4*)(Bp + 12);
  for (int k0 = 0; k0 < K; k0 += 64) {
    __syncthreads();
    *(ushort4*)(As_w +  0) = ushort4{f2bf(pa0.x), f2bf(pa0.y), f2bf(pa0.z), f2bf(pa0.w)};
    *(ushort4*)(As_w +  4) = ushort4{f2bf(pa1.x), f2bf(pa1.y), f2bf(pa1.z), f2bf(pa1.w)};
    *(ushort4*)(As_w +  8) = ushort4{f2bf(pa2.x), f2bf(pa2.y), f2bf(pa2.z), f2bf(pa2.w)};
    *(ushort4*)(As_w + 12) = ushort4{f2bf(pa3.x), f2bf(pa3.y), f2bf(pa3.z), f2bf(pa3.w)};
    *(ushort4*)(Bs_w +  0) = ushort4{f2bf(pb0.x), f2bf(pb0.y), f2bf(pb0.z), f2bf(pb0.w)};
    *(ushort4*)(Bs_w +  4) = ushort4{f2bf(pb1.x), f2bf(pb1.y), f2bf(pb1.z), f2bf(pb1.w)};
    *(ushort4*)(Bs_w +  8) = ushort4{f2bf(pb2.x), f2bf(pb2.y), f2bf(pb2.z), f2bf(pb2.w)};
    *(ushort4*)(Bs_w + 12) = ushort4{f2bf(pb3.x), f2bf(pb3.y), f2bf(pb3.z), f2bf(pb3.w)};
    __syncthreads();
    if (k0 + 64 < K) {
      pa0 = *(const float4*)(Ap + k0 + 64);
      pa1 = *(const float4*)(Ap + k0 + 68);
      pa2 = *(const float4*)(Ap + k0 + 72);
      pa3 = *(const float4*)(Ap + k0 + 76);
      pb0 = *(const float4*)(Bp + k0 + 64);
      pb1 = *(const float4*)(Bp + k0 + 68);
      pb2 = *(const float4*)(Bp + k0 + 72);
      pb3 = *(const float4*)(Bp + k0 + 76);
    }
#pragma unroll
    for (int s = 0; s < 2; s++) {
      bf16x8 af0 = *(const bf16x8*)(As_r + s * 32);
      bf16x8 af1 = *(const bf16x8*)(As_r + s * 32 + 16 * 72);
      bf16x8 bg0 = *(const bf16x8*)(Bs_r + s * 32);
      bf16x8 bg1 = *(const bf16x8*)(Bs_r + s * 32 + 16 * 72);
      acc[0][0] = __builtin_amdgcn_mfma_f32_16x16x32_bf16(af0, bg0, acc[0][0], 0, 0, 0);
      acc[0][1] = __builtin_amdgcn_mfma_f32_16x16x32_bf16(af0, bg1, acc[0][1], 0, 0, 0);
      acc[1][0] = __builtin_amdgcn_mfma_f32_16x16x32_bf16(af1, bg0, acc[1][0], 0, 0, 0);
      acc[1][1] = __builtin_amdgcn_mfma_f32_16x16x32_bf16(af1, bg1, acc[1][1], 0, 0, 0);
    }
  }
  int col0 = bx + wc * 32 + (lane & 15);
  int row0 = by + wr * 32 + ((lane >> 4) * 4);
#pragma unroll
  for (int ni = 0; ni < 2; ni++) {
    int col = col0 + ni * 16;
    float bi = bias ? bias[col] : 0.f;
#pragma unroll
    for (int mi = 0; mi < 2; mi++) {
#pragma unroll
      for (int j = 0; j < 4; j++) {
        int row = row0 + mi * 16 + j;
        float v = acc[mi][ni][j] + bi;
        if (ACT == 1) v = fmaxf(v, 0.f);
        if (OUT_BF16)
          ((unsigned short*)Cout)[(size_t)row * ldc + col] = f2bf(v);
        else
          ((float*)Cout)[(size_t)row * ldc + col] = v;
      }
    }
  }
}

// ---------------------------------------------------------------------------
// Tiled attention: block = 32 q-rows x (head, batch). S compile-time.
// ---------------------------------------------------------------------------
template <int S, int OBF>
__global__ __launch_bounds__(256) void attn_tile_kernel(
    const float* __restrict__ qkv, void* __restrict__ ctx, int rowoff) {
  constexpr int KLEN = S / 8;
  int xt = blockIdx.x, h = blockIdx.y, b = blockIdx.z;
  int rowbase = rowoff + b * S;
  int q0 = xt * 32;
  const float* base = qkv + (size_t)rowbase * 1536;
  int tid = threadIdx.x;
  __shared__ float qs[32][66];
  __shared__ float sc[32][S + 1];
  __shared__ float redm[32][8], redsum[32][8];
  for (int i = tid; i < 512; i += 256) {
    int qi = i >> 4, d4 = (i & 15) * 4;
    float4 v = *(const float4*)(base + (size_t)(q0 + qi) * 1536 + h * 64 + d4);
    qs[qi][d4 + 0] = v.x; qs[qi][d4 + 1] = v.y;
    qs[qi][d4 + 2] = v.z; qs[qi][d4 + 3] = v.w;
  }
  __syncthreads();
  int qi = tid & 31, kg = tid >> 5;
  float sloc[KLEN];
  float m = -1e30f;
#pragma unroll
  for (int kk = 0; kk < KLEN; kk++) {
    int k = kg * KLEN + kk;
    const float4* kr = (const float4*)(base + (size_t)k * 1536 + 512 + h * 64);
    float acc = 0.f;
#pragma unroll
    for (int d = 0; d < 16; d++) {
      float4 kv = kr[d];
      acc += qs[qi][d * 4 + 0] * kv.x + qs[qi][d * 4 + 1] * kv.y +
             qs[qi][d * 4 + 2] * kv.z + qs[qi][d * 4 + 3] * kv.w;
    }
    acc *= 0.125f;
    sloc[kk] = acc;
    m = fmaxf(m, acc);
  }
  redm[qi][kg] = m;
  __syncthreads();
  float M = redm[qi][0];
#pragma unroll
  for (int g = 1; g < 8; g++) M = fmaxf(M, redm[qi][g]);
  float ssum = 0.f;
#pragma unroll
  for (int kk = 0; kk < KLEN; kk++) {
    float e = __expf(sloc[kk] - M);
    sc[qi][kg * KLEN + kk] = e;
    ssum += e;
  }
  redsum[qi][kg] = ssum;
  __syncthreads();
  float sum = redsum[qi][0];
#pragma unroll
  for (int g = 1; g < 8; g++) sum += redsum[qi][g];
  float inv = 1.f / sum;
  int d0 = kg * 8;
  float a8[8] = {};
  for (int k = 0; k < S; k++) {
    float p = sc[qi][k];
    const float4* vr = (const float4*)(base + (size_t)k * 1536 + 1024 + h * 64 + d0);
    float4 v0 = vr[0], v1 = vr[1];
    a8[0] += p * v0.x; a8[1] += p * v0.y; a8[2] += p * v0.z; a8[3] += p * v0.w;
    a8[4] += p * v1.x; a8[5] += p * v1.y; a8[6] += p * v1.z; a8[7] += p * v1.w;
  }
  size_t obase = ((size_t)(rowbase + q0 + qi)) * HD + h * 64 + d0;
#pragma unroll
  for (int j = 0; j < 8; j++) {
    float c = a8[j] * inv;
    if (OBF) ((unsigned short*)ctx)[obase + j] = f2bf(c);
    else     ((float*)ctx)[obase + j] = c;
  }
}

// ---------------------------------------------------------------------------
// Residual add + LayerNorm (two-part); sums nparts partials of y.
// ---------------------------------------------------------------------------
__global__ __launch_bounds__(256) void add_ln_kernel(
    float* __restrict__ x, const float* __restrict__ y, int nparts,
    size_t pstride,
    const float* __restrict__ s0, const float* __restrict__ b0,
    const float* __restrict__ s1, const float* __restrict__ b1,
    unsigned short* __restrict__ xbf) {
  int row = blockIdx.x, tid = threadIdx.x;
  const float* s = (row < 1024) ? s0 : s1;
  const float* bsh = (row < 1024) ? b0 : b1;
  float* xr = x + (size_t)row * HD;
  float v0 = xr[tid];
  float v1 = xr[tid + 256];
  for (int p = 0; p < nparts; p++) {
    const float* yr = y + p * pstride + (size_t)row * HD;
    v0 += yr[tid];
    v1 += yr[tid + 256];
  }
  __shared__ float rs_[256], rq_[256];
  rs_[tid] = v0 + v1;
  rq_[tid] = v0 * v0 + v1 * v1;
  __syncthreads();
  for (int st = 128; st > 0; st >>= 1) {
    if (tid < st) { rs_[tid] += rs_[tid + st]; rq_[tid] += rq_[tid + st]; }
    __syncthreads();
  }
  float mean = rs_[0] * (1.f / HD);
  float var = rq_[0] * (1.f / HD) - mean * mean;
  float rstd = rsqrtf(var + 1e-5f);
  float o0 = (v0 - mean) * rstd * s[tid] + bsh[tid];
  float o1 = (v1 - mean) * rstd * s[tid + 256] + bsh[tid + 256];
  xr[tid] = o0;
  xr[tid + 256] = o1;
  if (xbf) {
    xbf[(size_t)row * HD + tid] = f2bf(o0);
    xbf[(size_t)row * HD + tid + 256] = f2bf(o1);
  }
}

// ---------------------------------------------------------------------------
// Joint v6: packed-W, 128x512 blocks, 8 waves of 64x128, acc[4][8],
// 2-pass LSE via partials + finish kernel.
// ---------------------------------------------------------------------------
__global__ __launch_bounds__(512, 2) void joint_fused_kernel(
    const unsigned short* __restrict__ ha, const unsigned short* __restrict__ hl,
    const unsigned short* __restrict__ W, const float* __restrict__ wb,
    float* __restrict__ out, float* __restrict__ pmax, float* __restrict__ psum) {
  __shared__ char AsB[128 * 128];
  __shared__ float redm[128 * 4];
  __shared__ float reds[128 * 4];
  int tid = threadIdx.x;
  int colblk = blockIdx.x;
  int m0 = blockIdx.y * 128;
  int b = m0 >> 14;
  int lane = tid & 63, w = tid >> 6;
  int wave_r = w >> 2, wc2 = w & 3;

  int arow = tid >> 2;
  int ak = (tid & 3) * 16;
  int bt = (m0 + arow) >> 6;
  int u_s = arow & 63;
  const unsigned short* ha_p = ha + (size_t)bt * KJOINT + ak;
  const unsigned short* hl_p = hl + (size_t)(b * 64 + u_s) * KJOINT + ak;
  int aswz = (arow & 7) << 4;
  char* As_w0 = AsB + arow * 128 + ((ak * 2) ^ aswz);
  char* As_w1 = AsB + arow * 128 + (((ak * 2) + 16) ^ aswz);

  int frow = wave_r * 64 + (lane & 15);
  int fswz = ((lane & 7) << 4);
  const char* As_rh0 = AsB + frow * 128 + (((lane >> 4) * 32) ^ fswz);
  const char* As_rh1 = AsB + frow * 128 + ((((lane >> 4) * 32) + 16) ^ fswz);

  const unsigned short* Wl = W + ((size_t)(colblk * 32 + wc2 * 8) * 32) * 1024 +
                             (size_t)lane * 8;

  f32x4 acc[4][8] = {};
  for (int k0 = 0; k0 < KJOINT; k0 += 64) {
    int ksoff = (k0 >> 6) * 1024;
    bf16x8 b0[8], b1[8];
#pragma unroll
    for (int ni = 0; ni < 8; ni++) {
      const unsigned short* p = Wl + (size_t)ni * 32768 + ksoff;
      b0[ni] = *(const bf16x8*)(p);
      b1[ni] = *(const bf16x8*)(p + 512);
    }
    bf16x8 av0 = *(const bf16x8*)(ha_p + k0);
    bf16x8 av1 = *(const bf16x8*)(ha_p + k0 + 8);
    bf16x8 lv0 = *(const bf16x8*)(hl_p + k0);
    bf16x8 lv1 = *(const bf16x8*)(hl_p + k0 + 8);
    short hv0[8], hv1[8];
#pragma unroll
    for (int j = 0; j < 8; j++) {
      hv0[j] = (short)f2bf(fast_tanh(bf2f((unsigned short)av0[j]) +
                                     bf2f((unsigned short)lv0[j])));
      hv1[j] = (short)f2bf(fast_tanh(bf2f((unsigned short)av1[j]) +
                                     bf2f((unsigned short)lv1[j])));
    }
    __syncthreads();
    *(bf16x8*)As_w0 = *(const bf16x8*)hv0;
    *(bf16x8*)As_w1 = *(const bf16x8*)hv1;
    __syncthreads();
#pragma unroll
    for (int mi = 0; mi < 4; mi++) {
      bf16x8 af = *(const bf16x8*)(As_rh0 + mi * 16 * 128);
#pragma unroll
      for (int ni = 0; ni < 8; ni++)
        acc[mi][ni] = __builtin_amdgcn_mfma_f32_16x16x32_bf16(
            af, b0[ni], acc[mi][ni], 0, 0, 0);
    }
#pragma unroll
    for (int mi = 0; mi < 4; mi++) {
      bf16x8 af = *(const bf16x8*)(As_rh1 + mi * 16 * 128);
#pragma unroll
      for (int ni = 0; ni < 8; ni++)
        acc[mi][ni] = __builtin_amdgcn_mfma_f32_16x16x32_bf16(
            af, b1[ni], acc[mi][ni], 0, 0, 0);
    }
  }

  int coll = colblk * 512 + wc2 * 128 + (lane & 15);
  float bv[8];
#pragma unroll
  for (int ni = 0; ni < 8; ni++) bv[ni] = wb[coll + ni * 16];
#pragma unroll
  for (int mi = 0; mi < 4; mi++)
#pragma unroll
    for (int ni = 0; ni < 8; ni++)
#pragma unroll
      for (int j = 0; j < 4; j++) acc[mi][ni][j] += bv[ni];

  int rbase = wave_r * 64 + ((lane >> 4) * 4);
  float rmax[4][4], rsum[4][4];
#pragma unroll
  for (int mi = 0; mi < 4; mi++) {
#pragma unroll
    for (int j = 0; j < 4; j++) {
      float m = acc[mi][0][j];
#pragma unroll
      for (int ni = 1; ni < 8; ni++) m = fmaxf(m, acc[mi][ni][j]);
      m = fmaxf(m, __shfl_xor(m, 1));
      m = fmaxf(m, __shfl_xor(m, 2));
      m = fmaxf(m, __shfl_xor(m, 4));
      m = fmaxf(m, __shfl_xor(m, 8));
      rmax[mi][j] = m;
      float s = 0.f;
#pragma unroll
      for (int ni = 0; ni < 8; ni++) s += __expf(acc[mi][ni][j] - m);
      s += __shfl_xor(s, 1);
      s += __shfl_xor(s, 2);
      s += __shfl_xor(s, 4);
      s += __shfl_xor(s, 8);
      rsum[mi][j] = s;
    }
  }
  if ((lane & 15) == 0) {
#pragma unroll
    for (int mi = 0; mi < 4; mi++)
#pragma unroll
      for (int j = 0; j < 4; j++) {
        redm[(rbase + mi * 16 + j) * 4 + wc2] = rmax[mi][j];
        reds[(rbase + mi * 16 + j) * 4 + wc2] = rsum[mi][j];
      }
  }
  __syncthreads();
  {
    int r2 = tid >> 2, c2 = tid & 3;
    float m = redm[r2 * 4 + c2];
    float M = fmaxf(m, __shfl_xor(m, 1));
    M = fmaxf(M, __shfl_xor(M, 2));
    float s = reds[r2 * 4 + c2] * __expf(m - M);
    s += __shfl_xor(s, 1);
    s += __shfl_xor(s, 2);
    if (c2 == 0) {
      pmax[(size_t)(m0 + r2) * 2 + colblk] = M;
      psum[(size_t)(m0 + r2) * 2 + colblk] = s;
    }
  }
#pragma unroll
  for (int mi = 0; mi < 4; mi++) {
#pragma unroll
    for (int j = 0; j < 4; j++) {
      size_t row = (size_t)m0 + rbase + mi * 16 + j;
#pragma unroll
      for (int ni = 0; ni < 8; ni++)
        out[row * VOUT + coll + ni * 16] = acc[mi][ni][j];
    }
  }
}

__global__ __launch_bounds__(256) void lse_finish_kernel(
    float* __restrict__ out, const float* __restrict__ pmax,
    const float* __restrict__ psum) {
  int r0 = blockIdx.x * 32;
  int tid = threadIdx.x;
  for (int i = 0; i < 32; i++) {
    int r = r0 + i;
    float m0 = pmax[(size_t)r * 2], m1 = pmax[(size_t)r * 2 + 1];
    float M = fmaxf(m0, m1);
    float S = psum[(size_t)r * 2] * __expf(m0 - M) +
              psum[(size_t)r * 2 + 1] * __expf(m1 - M);
    float lse = M + __logf(S);
    float4* p = (float4*)(out + (size_t)r * VOUT) + tid;
    float4 v = *p;
    v.x -= lse; v.y -= lse; v.z -= lse; v.w -= lse;
    *p = v;
  }
}

// ---------------------------------------------------------------------------
// Host side
// ---------------------------------------------------------------------------
extern "C" void kernel_launch(void* const* d_in, const int* in_sizes, int n_in,
                              void* d_out, int out_size, void* d_ws, size_t ws_size,
                              hipStream_t stream) {
  const int B = 4, T = 256, U = 64;
  const float* input_values = (const float*)d_in[0];
  const int* labels = (const int*)d_in[1];
  const float* a_lin_w = (const float*)d_in[4];
  const float* a_lin_b = (const float*)d_in[5];
  const float* a_pos = (const float*)d_in[6];
  const float* l_word = (const float*)d_in[7];
  const float* l_pos = (const float*)d_in[8];
  const float* joint_w = (const float*)d_in[9];
  const float* joint_b = (const float*)d_in[10];
  const float* out_w = (const float*)d_in[11];
  const float* out_b = (const float*)d_in[12];

  const float* a_qkv_w = (const float*)d_in[13];
  const float* a_qkv_b = (const float*)d_in[14];
  const float* a_out_w = (const float*)d_in[15];
  const float* a_out_b = (const float*)d_in[16];
  const float* a_ff1_w = (const float*)d_in[17];
  const float* a_ff1_b = (const float*)d_in[18];
  const float* a_ff2_w = (const float*)d_in[19];
  const float* a_ff2_b = (const float*)d_in[20];
  const float* a_ln1_s = (const float*)d_in[21];
  const float* a_ln1_b = (const float*)d_in[22];
  const float* a_ln2_s = (const float*)d_in[23];
  const float* a_ln2_b = (const float*)d_in[24];
  const float* l_qkv_w = (const float*)d_in[25];
  const float* l_qkv_b = (const float*)d_in[26];
  const float* l_out_w = (const float*)d_in[27];
  const float* l_out_b = (const float*)d_in[28];
  const float* l_ff1_w = (const float*)d_in[29];
  const float* l_ff1_b = (const float*)d_in[30];
  const float* l_ff2_w = (const float*)d_in[31];
  const float* l_ff2_b = (const float*)d_in[32];
  const float* l_ln1_s = (const float*)d_in[33];
  const float* l_ln1_b = (const float*)d_in[34];
  const float* l_ln2_s = (const float*)d_in[35];
  const float* l_ln2_b = (const float*)d_in[36];

  float* ws = (float*)d_ws;
  float* x_all = ws;                       // 655360
  float* qkv   = x_all + 655360;           // 1966080
  float* tmp   = qkv + 1966080;            // 2621440
  float* pmax  = tmp + 2621440;            // 131072
  float* psum  = pmax + 131072;            // 131072
  size_t off = 5505024;

  unsigned short* x_bf   = (unsigned short*)(ws + off);            // 327680 f
  unsigned short* ctx_bf = (unsigned short*)(ws + off + 327680);   // 327680 f
  unsigned short* ff1_bf = (unsigned short*)(ws + off + 655360);   // 1310720 f
  unsigned short* ha_bf  = (unsigned short*)(ws + off + 1966080);  // 1048576 f
  unsigned short* hl_bf  = (unsigned short*)(ws + off + 3014656);  // 262144 f
  unsigned short* Wb     = (unsigned short*)(ws + off + 3276800);  // 1048576 f
  size_t woff = off + 4325376;
  unsigned short* a_qkv_wb = (unsigned short*)(ws + woff);               // 4718592 f
  unsigned short* a_out_wb = (unsigned short*)(ws + woff + 4718592);     // 1572864 f
  unsigned short* a_ff1_wb = (unsigned short*)(ws + woff + 6291456);     // 6291456 f
  unsigned short* a_ff2_wb = (unsigned short*)(ws + woff + 12582912);    // 6291456 f
  unsigned short* l_qkv_wb = (unsigned short*)(ws + woff + 18874368);    // 1572864 f
  unsigned short* l_out_wb = (unsigned short*)(ws + woff + 20447232);    // 524288 f
  unsigned short* l_ff1_wb = (unsigned short*)(ws + woff + 20971520);    // 2097152 f
  unsigned short* l_ff2_wb = (unsigned short*)(ws + woff + 23068672);    // 2097152 f
  unsigned short* Wa_pk    = (unsigned short*)(ws + woff + 25165824);    // 524288 f
  unsigned short* Wl_pk    = (unsigned short*)(ws + woff + 25690112);    // 524288 f
  size_t need_floats = woff + 26214400;
  bool fast = ws_size >= need_floats * sizeof(float);

  if (fast) {
    // ---- pack all weights into fragment order ----
    pack_w_kernel<<<12 * 1536 * 512 / 2048, 256, 0, stream>>>(a_qkv_w, 512, 512, a_qkv_wb);
    pack_w_kernel<<<12 * 512 * 512 / 2048, 256, 0, stream>>>(a_out_w, 512, 512, a_out_wb);
    pack_w_kernel<<<12 * 2048 * 512 / 2048, 256, 0, stream>>>(a_ff1_w, 512, 512, a_ff1_wb);
    pack_w_kernel<<<12 * 512 * 2048 / 2048, 256, 0, stream>>>(a_ff2_w, 2048, 2048, a_ff2_wb);
    pack_w_kernel<<<4 * 1536 * 512 / 2048, 256, 0, stream>>>(l_qkv_w, 512, 512, l_qkv_wb);
    pack_w_kernel<<<4 * 512 * 512 / 2048, 256, 0, stream>>>(l_out_w, 512, 512, l_out_wb);
    pack_w_kernel<<<4 * 2048 * 512 / 2048, 256, 0, stream>>>(l_ff1_w, 512, 512, l_ff1_wb);
    pack_w_kernel<<<4 * 512 * 2048 / 2048, 256, 0, stream>>>(l_ff2_w, 2048, 2048, l_ff2_wb);
    pack_w_kernel<<<2048 * 512 / 2048, 256, 0, stream>>>(joint_w, 1024, 512, Wa_pk);
    pack_w_kernel<<<2048 * 512 / 2048, 256, 0, stream>>>(joint_w + 512, 1024, 512, Wl_pk);
    pack_w_kernel<<<1024 * 2048 / 2048, 256, 0, stream>>>(out_w, 2048, 2048, Wb);

    // ---- embeddings ----
    embed_audio_kernel<<<B * T, 256, 0, stream>>>(
        input_values, a_lin_w, a_lin_b, a_pos, x_all, x_bf, T);
    embed_label_kernel<<<B * U, 256, 0, stream>>>(
        labels, l_word, l_pos, x_all + 1024 * HD, x_bf + 1024 * HD, U);

    // ---- merged encoder layers ----
    for (int l = 0; l < 12; l++) {
      bool both = (l < 4);
      int M = both ? 1280 : 1024;
      int gy = M / 64;
      const unsigned short* qw1 = both ? l_qkv_wb + (size_t)l * 1536 * HD : a_qkv_wb;
      const float* qb1 = both ? l_qkv_b + (size_t)l * 1536 : a_qkv_b;
      const unsigned short* ow1 = both ? l_out_wb + (size_t)l * HD * HD : a_out_wb;
      const float* ob1 = both ? l_out_b + (size_t)l * HD : a_out_b;
      const unsigned short* f1w1 = both ? l_ff1_wb + (size_t)l * FF * HD : a_ff1_wb;
      const float* f1b1 = both ? l_ff1_b + (size_t)l * FF : a_ff1_b;
      const unsigned short* f2w1 = both ? l_ff2_wb + (size_t)l * HD * FF : a_ff2_wb;
      const float* f2b1 = both ? l_ff2_b + (size_t)l * HD : a_ff2_b;
      const float* n1s1 = both ? l_ln1_s + (size_t)l * HD : a_ln1_s;
      const float* n1b1 = both ? l_ln1_b + (size_t)l * HD : a_ln1_b;
      const float* n2s1 = both ? l_ln2_s + (size_t)l * HD : a_ln2_s;
      const float* n2b1 = both ? l_ln2_b + (size_t)l * HD : a_ln2_b;

      gemmp_kernel<0, 0><<<dim3(1536 / 64, gy, 1), 256, 0, stream>>>(
          x_bf, HD, a_qkv_wb + (size_t)l * 1536 * HD, qw1,
          a_qkv_b + (size_t)l * 1536, qb1, qkv, 1536, HD, 1024, 8, 0);
      attn_tile_kernel<256, 1><<<dim3(8, 8, B), 256, 0, stream>>>(qkv, ctx_bf, 0);
      if (both)
        attn_tile_kernel<64, 1><<<dim3(2, 8, B), 256, 0, stream>>>(qkv, ctx_bf, 1024);
      gemmp_kernel<0, 0><<<dim3(HD / 64, gy, 2), 256, 0, stream>>>(
          ctx_bf, HD, a_out_wb + (size_t)l * HD * HD, ow1,
          a_out_b + (size_t)l * HD, ob1, tmp, HD, HD, 1024, 4, 655360);
      add_ln_kernel<<<M, 256, 0, stream>>>(x_all, tmp, 2, 655360,
          a_ln1_s + (size_t)l * HD, a_ln1_b + (size_t)l * HD, n1s1, n1b1, x_bf);
      gemmp_kernel<1, 1><<<dim3(FF / 64, gy, 1), 256, 0, stream>>>(
          x_bf, HD, a_ff1_wb + (size_t)l * FF * HD, f1w1,
          a_ff1_b + (size_t)l * FF, f1b1, ff1_bf, FF, HD, 1024, 8, 0);
      gemmp_kernel<0, 0><<<dim3(HD / 64, gy, 4), 256, 0, stream>>>(
          ff1_bf, FF, a_ff2_wb + (size_t)l * HD * FF, f2w1,
          a_ff2_b + (size_t)l * HD, f2b1, tmp, HD, FF, 1024, 8, 655360);
      add_ln_kernel<<<M, 256, 0, stream>>>(x_all, tmp, 4, 655360,
          a_ln2_s + (size_t)l * HD, a_ln2_b + (size_t)l * HD, n2s1, n2b1, x_bf);
    }

    // ---- joint projections -> bf16 ----
    gemmp_kernel<0, 1><<<dim3(KJOINT / 64, 1024 / 64, 1), 256, 0, stream>>>(
        x_bf, HD, Wa_pk, Wa_pk, nullptr, nullptr, ha_bf, KJOINT, HD, 1 << 30, 8, 0);
    gemmp_kernel<0, 1><<<dim3(KJOINT / 64, 256 / 64, 1), 256, 0, stream>>>(
        x_bf + (size_t)1024 * HD, HD, Wl_pk, Wl_pk, joint_b, joint_b,
        hl_bf, KJOINT, HD, 1 << 30, 8, 0);

    joint_fused_kernel<<<dim3(2, 512), 512, 0, stream>>>(
        ha_bf, hl_bf, Wb, out_b, (float*)d_out, pmax, psum);
    lse_finish_kernel<<<(B * T * U) / 32, 256, 0, stream>>>(
        (float*)d_out, pmax, psum);
  } else {
    // ---- fallback: f32-staging path (small workspace) ----
    float* ctx = ws + off;
    float* ff1 = ctx + 655360;
    unsigned short* ha_bf2 = (unsigned short*)qkv;
    unsigned short* hl_bf2 = (unsigned short*)(qkv + 1048576);
    unsigned short* Wb2 = (unsigned short*)(qkv + 1310720);

    embed_audio_kernel<<<B * T, 256, 0, stream>>>(
        input_values, a_lin_w, a_lin_b, a_pos, x_all, nullptr, T);
    embed_label_kernel<<<B * U, 256, 0, stream>>>(
        labels, l_word, l_pos, x_all + 1024 * HD, nullptr, U);

    for (int l = 0; l < 12; l++) {
      bool both = (l < 4);
      int M = both ? 1280 : 1024;
      int gy = M / 64;
      const float* qw1 = both ? l_qkv_w + (size_t)l * 1536 * HD : a_qkv_w;
      const float* qb1 = both ? l_qkv_b + (size_t)l * 1536 : a_qkv_b;
      const float* ow1 = both ? l_out_w + (size_t)l * HD * HD : a_out_w;
      const float* ob1 = both ? l_out_b + (size_t)l * HD : a_out_b;
      const float* f1w1 = both ? l_ff1_w + (size_t)l * FF * HD : a_ff1_w;
      const float* f1b1 = both ? l_ff1_b + (size_t)l * FF : a_ff1_b;
      const float* f2w1 = both ? l_ff2_w + (size_t)l * HD * FF : a_ff2_w;
      const float* f2b1 = both ? l_ff2_b + (size_t)l * HD : a_ff2_b;
      const float* n1s1 = both ? l_ln1_s + (size_t)l * HD : a_ln1_s;
      const float* n1b1 = both ? l_ln1_b + (size_t)l * HD : a_ln1_b;
      const float* n2s1 = both ? l_ln2_s + (size_t)l * HD : a_ln2_s;
      const float* n2b1 = both ? l_ln2_b + (size_t)l * HD : a_ln2_b;

      gemm64_kernel<0, 0><<<dim3(1536 / 64, gy), 256, 0, stream>>>(
          x_all, HD, a_qkv_w + (size_t)l * 1536 * HD, qw1, HD,
          a_qkv_b + (size_t)l * 1536, qb1, qkv, 1536, 1536, HD, 1024);
      attn_tile_kernel<256, 0><<<dim3(8, 8, B), 256, 0, stream>>>(qkv, ctx, 0);
      if (both)
        attn_tile_kernel<64, 0><<<dim3(2, 8, B), 256, 0, stream>>>(qkv, ctx, 1024);
      gemm64_kernel<0, 0><<<dim3(HD / 64, gy), 256, 0, stream>>>(
          ctx, HD, a_out_w + (size_t)l * HD * HD, ow1, HD,
          a_out_b + (size_t)l * HD, ob1, tmp, HD, HD, HD, 1024);
      add_ln_kernel<<<M, 256, 0, stream>>>(x_all, tmp, 1, 0,
          a_ln1_s + (size_t)l * HD, a_ln1_b + (size_t)l * HD, n1s1, n1b1, nullptr);
      gemm64_kernel<1, 0><<<dim3(FF / 64, gy), 256, 0, stream>>>(
          x_all, HD, a_ff1_w + (size_t)l * FF * HD, f1w1, HD,
          a_ff1_b + (size_t)l * FF, f1b1, ff1, FF, FF, HD, 1024);
      gemm64_kernel<0, 0><<<dim3(HD / 64, gy), 256, 0, stream>>>(
          ff1, FF, a_ff2_w + (size_t)l * HD * FF, f2w1, FF,
          a_ff2_b + (size_t)l * HD, f2b1, tmp, HD, HD, FF, 1024);
      add_ln_kernel<<<M, 256, 0, stream>>>(x_all, tmp, 1, 0,
          a_ln2_s + (size_t)l * HD, a_ln2_b + (size_t)l * HD, n2s1, n2b1, nullptr);
    }

    pack_w_kernel<<<1024 * 2048 / 2048, 256, 0, stream>>>(out_w, 2048, 2048, Wb2);
    gemm64_kernel<0, 1><<<dim3(KJOINT / 64, 1024 / 64), 256, 0, stream>>>(
        x_all, HD, joint_w, joint_w, 1024, nullptr, nullptr,
        ha_bf2, KJOINT, KJOINT, HD, 1 << 30);
    gemm64_kernel<0, 1><<<dim3(KJOINT / 64, 256 / 64), 256, 0, stream>>>(
        x_all + 1024 * HD, HD, joint_w + HD, joint_w + HD, 1024, joint_b,
        joint_b, hl_bf2, KJOINT, KJOINT, HD, 1 << 30);

    joint_fused_kernel<<<dim3(2, 512), 512, 0, stream>>>(
        ha_bf2, hl_bf2, Wb2, out_b, (float*)d_out, pmax, psum);
    lse_finish_kernel<<<(B * T * U) / 32, 256, 0, stream>>>(
        (float*)d_out, pmax, psum);
  }
}